// Round 1
// baseline (1143.699 us; speedup 1.0000x reference)
//
#include <hip/hip_runtime.h>
#include <cstdint>
#include <cstddef>

#define T_TOK 10
#define NH 12
#define DH 32
#define DIM 384
#define QKVDIM 1152
#define NB 4            // batches per workgroup
#define MROWS 40        // valid rows per WG
#define XS_LD 392       // bf16 elems per row of x/O staging (384 + 8 pad)
#define QKV_LD 1160     // bf16 elems per row of qkv staging (1152 + 8 pad)
#define SCALE 0.17677669529663689f   // 32^-0.5

// LDS layout (bytes):
//   [0, 37632)          xs   [48][392] bf16   (later aliased as Os, attn output)
//   [37632, 130432)     qkvs [40][1160] bf16  (later aliased as outstage [40][384] f32)
//   [130432, 131344)    bias_lds [19*12] f32
#define LDS_BYTES 131344

typedef short bf16x8 __attribute__((ext_vector_type(8)));
typedef float f32x4  __attribute__((ext_vector_type(4)));

__device__ __forceinline__ unsigned short f2b(float f) {
    unsigned u = __float_as_uint(f);
    u = (u + 0x7FFFu + ((u >> 16) & 1u)) >> 16;   // RNE
    return (unsigned short)u;
}
__device__ __forceinline__ float b2f(unsigned short h) {
    return __uint_as_float(((unsigned)h) << 16);
}
__device__ __forceinline__ unsigned pack2(float a, float b) {
    return (unsigned)f2b(a) | ((unsigned)f2b(b) << 16);
}

// ---------------- K0: convert weights fp32 -> bf16 into workspace ----------------
__global__ void convert_weights(const float* __restrict__ qkv_w,
                                const float* __restrict__ proj_w,
                                unsigned short* __restrict__ wq,
                                unsigned short* __restrict__ wp) {
    int i = blockIdx.x * blockDim.x + threadIdx.x;   // unit = 4 floats
    const int N1 = QKVDIM * DIM / 4;                 // 110592
    const int N2 = DIM * DIM / 4;                    // 36864
    if (i < N1) {
        float4 v = ((const float4*)qkv_w)[i];
        uint2 o; o.x = pack2(v.x, v.y); o.y = pack2(v.z, v.w);
        ((uint2*)wq)[i] = o;
    } else if (i < N1 + N2) {
        int j = i - N1;
        float4 v = ((const float4*)proj_w)[j];
        uint2 o; o.x = pack2(v.x, v.y); o.y = pack2(v.z, v.w);
        ((uint2*)wp)[j] = o;
    }
}

// ---------------- K1: fused qkv-gemm + attention + proj ----------------
extern __shared__ char smem[];

__global__ __launch_bounds__(256, 1) void fused_attn(
    const float* __restrict__ x,
    const float* __restrict__ qkv_b,
    const float* __restrict__ proj_b,
    const float* __restrict__ bias_table,
    const unsigned short* __restrict__ wq,
    const unsigned short* __restrict__ wp,
    float* __restrict__ out)
{
    const int t    = threadIdx.x;
    const int wg   = blockIdx.x;
    const int wave = t >> 6;
    const int lane = t & 63;
    const int quad = lane >> 4;
    const int l16  = lane & 15;

    unsigned short* xs       = (unsigned short*)smem;                 // [48][392]
    unsigned short* qkvs     = (unsigned short*)(smem + 37632);       // [40][1160]
    float*          outstage = (float*)(smem + 37632);                // [40][384] (alias)
    float*          bias_lds = (float*)(smem + 130432);               // [228]

    // ---------- phase 0: stage x -> LDS bf16, zero pad rows, load bias table ----------
    {
        const float4* x4 = (const float4*)(x + (size_t)wg * MROWS * DIM);
        #pragma unroll
        for (int i = 0; i < 15; ++i) {
            int idx = i * 256 + t;               // 0 .. 3839  (= 40*96)
            int row = idx / 96, c4 = idx % 96;
            float4 v = x4[idx];
            uint2 o; o.x = pack2(v.x, v.y); o.y = pack2(v.z, v.w);
            *(uint2*)(xs + row * XS_LD + c4 * 4) = o;
        }
        // zero rows 40..47 (full 392 cols, 4 elems per store)
        for (int idx = t; idx < 8 * 98; idx += 256) {
            int row = MROWS + idx / 98, c4 = idx % 98;
            *(uint2*)(xs + row * XS_LD + c4 * 4) = make_uint2(0u, 0u);
        }
        if (t < (2 * T_TOK - 1) * NH) bias_lds[t] = bias_table[t];
    }
    __syncthreads();

    // ---------- phase 1: QKV GEMM into qkvs (q pre-scaled, bias added) ----------
    {
        #pragma unroll 1
        for (int g = 0; g < 6; ++g) {
            f32x4 acc[3][3] = {};
            #pragma unroll
            for (int kc = 0; kc < 12; ++kc) {
                int koff = kc * 32 + quad * 8;
                bf16x8 a0 = *(const bf16x8*)(xs + ( 0 + l16) * XS_LD + koff);
                bf16x8 a1 = *(const bf16x8*)(xs + (16 + l16) * XS_LD + koff);
                bf16x8 a2 = *(const bf16x8*)(xs + (32 + l16) * XS_LD + koff);
                bf16x8 b0 = *(const bf16x8*)(wq + (size_t)((wave + 4*(3*g+0))*16 + l16) * DIM + koff);
                bf16x8 b1 = *(const bf16x8*)(wq + (size_t)((wave + 4*(3*g+1))*16 + l16) * DIM + koff);
                bf16x8 b2 = *(const bf16x8*)(wq + (size_t)((wave + 4*(3*g+2))*16 + l16) * DIM + koff);
                acc[0][0] = __builtin_amdgcn_mfma_f32_16x16x32_bf16(a0, b0, acc[0][0], 0, 0, 0);
                acc[0][1] = __builtin_amdgcn_mfma_f32_16x16x32_bf16(a0, b1, acc[0][1], 0, 0, 0);
                acc[0][2] = __builtin_amdgcn_mfma_f32_16x16x32_bf16(a0, b2, acc[0][2], 0, 0, 0);
                acc[1][0] = __builtin_amdgcn_mfma_f32_16x16x32_bf16(a1, b0, acc[1][0], 0, 0, 0);
                acc[1][1] = __builtin_amdgcn_mfma_f32_16x16x32_bf16(a1, b1, acc[1][1], 0, 0, 0);
                acc[1][2] = __builtin_amdgcn_mfma_f32_16x16x32_bf16(a1, b2, acc[1][2], 0, 0, 0);
                acc[2][0] = __builtin_amdgcn_mfma_f32_16x16x32_bf16(a2, b0, acc[2][0], 0, 0, 0);
                acc[2][1] = __builtin_amdgcn_mfma_f32_16x16x32_bf16(a2, b1, acc[2][1], 0, 0, 0);
                acc[2][2] = __builtin_amdgcn_mfma_f32_16x16x32_bf16(a2, b2, acc[2][2], 0, 0, 0);
            }
            #pragma unroll
            for (int j = 0; j < 3; ++j) {
                int n = (wave + 4*(3*g+j)) * 16 + l16;
                float qb = qkv_b[n];
                float sc = (n < DIM) ? SCALE : 1.0f;
                #pragma unroll
                for (int mt = 0; mt < 3; ++mt) {
                    #pragma unroll
                    for (int r = 0; r < 4; ++r) {
                        int m = mt * 16 + quad * 4 + r;
                        if (m < MROWS)
                            qkvs[m * QKV_LD + n] = f2b((acc[mt][j][r] + qb) * sc);
                    }
                }
            }
        }
    }
    __syncthreads();

    // ---------- phase 2: attention (VALU), writes O into xs region ----------
    if (t < 240) {
        int pr = t / 5, rp = t % 5;          // pair index, row-pair
        int bl = pr / NH, h = pr % NH;       // local batch, head
        int m0 = bl * T_TOK + rp * 2;
        int ti0 = rp * 2, ti1 = rp * 2 + 1;

        float q0[DH], q1[DH];
        const unsigned* qp0 = (const unsigned*)(qkvs + m0 * QKV_LD + h * DH);
        const unsigned* qp1 = (const unsigned*)(qkvs + (m0 + 1) * QKV_LD + h * DH);
        #pragma unroll
        for (int u = 0; u < 16; ++u) {
            unsigned w0 = qp0[u], w1 = qp1[u];
            q0[2*u] = b2f((unsigned short)w0); q0[2*u+1] = b2f((unsigned short)(w0 >> 16));
            q1[2*u] = b2f((unsigned short)w1); q1[2*u+1] = b2f((unsigned short)(w1 >> 16));
        }

        float s0[T_TOK], s1[T_TOK];
        #pragma unroll
        for (int j = 0; j < T_TOK; ++j) {
            const unsigned* kp = (const unsigned*)(qkvs + (bl * T_TOK + j) * QKV_LD + DIM + h * DH);
            float d0 = 0.f, d1 = 0.f;
            #pragma unroll
            for (int u = 0; u < 16; ++u) {
                unsigned w = kp[u];
                float e0 = b2f((unsigned short)w), e1 = b2f((unsigned short)(w >> 16));
                d0 += q0[2*u] * e0; d0 += q0[2*u+1] * e1;
                d1 += q1[2*u] * e0; d1 += q1[2*u+1] * e1;
            }
            s0[j] = d0 + bias_lds[(ti0 - j + T_TOK - 1) * NH + h];
            s1[j] = d1 + bias_lds[(ti1 - j + T_TOK - 1) * NH + h];
        }

        float mx0 = s0[0], mx1 = s1[0];
        #pragma unroll
        for (int j = 1; j < T_TOK; ++j) { mx0 = fmaxf(mx0, s0[j]); mx1 = fmaxf(mx1, s1[j]); }
        float sum0 = 0.f, sum1 = 0.f;
        #pragma unroll
        for (int j = 0; j < T_TOK; ++j) {
            s0[j] = __expf(s0[j] - mx0); sum0 += s0[j];
            s1[j] = __expf(s1[j] - mx1); sum1 += s1[j];
        }
        float r0 = 1.f / sum0, r1 = 1.f / sum1;

        float o0[DH] = {}, o1[DH] = {};
        #pragma unroll
        for (int j = 0; j < T_TOK; ++j) {
            const unsigned* vp = (const unsigned*)(qkvs + (bl * T_TOK + j) * QKV_LD + 2 * DIM + h * DH);
            float p0 = s0[j] * r0, p1 = s1[j] * r1;
            #pragma unroll
            for (int u = 0; u < 16; ++u) {
                unsigned w = vp[u];
                float e0 = b2f((unsigned short)w), e1 = b2f((unsigned short)(w >> 16));
                o0[2*u] += p0 * e0; o0[2*u+1] += p0 * e1;
                o1[2*u] += p1 * e0; o1[2*u+1] += p1 * e1;
            }
        }

        unsigned* os0 = (unsigned*)(xs + m0 * XS_LD + h * DH);
        unsigned* os1 = (unsigned*)(xs + (m0 + 1) * XS_LD + h * DH);
        #pragma unroll
        for (int u = 0; u < 16; ++u) {
            os0[u] = pack2(o0[2*u], o0[2*u+1]);
            os1[u] = pack2(o1[2*u], o1[2*u+1]);
        }
    }
    __syncthreads();

    // ---------- phase 3: proj GEMM (A = O in xs region), stage fp32 in qkvs region ----------
    {
        #pragma unroll 1
        for (int g = 0; g < 2; ++g) {
            f32x4 acc[3][3] = {};
            #pragma unroll
            for (int kc = 0; kc < 12; ++kc) {
                int koff = kc * 32 + quad * 8;
                bf16x8 a0 = *(const bf16x8*)(xs + ( 0 + l16) * XS_LD + koff);
                bf16x8 a1 = *(const bf16x8*)(xs + (16 + l16) * XS_LD + koff);
                bf16x8 a2 = *(const bf16x8*)(xs + (32 + l16) * XS_LD + koff);
                bf16x8 b0 = *(const bf16x8*)(wp + (size_t)((wave + 4*(3*g+0))*16 + l16) * DIM + koff);
                bf16x8 b1 = *(const bf16x8*)(wp + (size_t)((wave + 4*(3*g+1))*16 + l16) * DIM + koff);
                bf16x8 b2 = *(const bf16x8*)(wp + (size_t)((wave + 4*(3*g+2))*16 + l16) * DIM + koff);
                acc[0][0] = __builtin_amdgcn_mfma_f32_16x16x32_bf16(a0, b0, acc[0][0], 0, 0, 0);
                acc[0][1] = __builtin_amdgcn_mfma_f32_16x16x32_bf16(a0, b1, acc[0][1], 0, 0, 0);
                acc[0][2] = __builtin_amdgcn_mfma_f32_16x16x32_bf16(a0, b2, acc[0][2], 0, 0, 0);
                acc[1][0] = __builtin_amdgcn_mfma_f32_16x16x32_bf16(a1, b0, acc[1][0], 0, 0, 0);
                acc[1][1] = __builtin_amdgcn_mfma_f32_16x16x32_bf16(a1, b1, acc[1][1], 0, 0, 0);
                acc[1][2] = __builtin_amdgcn_mfma_f32_16x16x32_bf16(a1, b2, acc[1][2], 0, 0, 0);
                acc[2][0] = __builtin_amdgcn_mfma_f32_16x16x32_bf16(a2, b0, acc[2][0], 0, 0, 0);
                acc[2][1] = __builtin_amdgcn_mfma_f32_16x16x32_bf16(a2, b1, acc[2][1], 0, 0, 0);
                acc[2][2] = __builtin_amdgcn_mfma_f32_16x16x32_bf16(a2, b2, acc[2][2], 0, 0, 0);
            }
            #pragma unroll
            for (int j = 0; j < 3; ++j) {
                int c = (wave + 4*(3*g+j)) * 16 + l16;
                #pragma unroll
                for (int mt = 0; mt < 3; ++mt) {
                    #pragma unroll
                    for (int r = 0; r < 4; ++r) {
                        int m = mt * 16 + quad * 4 + r;
                        if (m < MROWS)
                            outstage[m * DIM + c] = acc[mt][j][r];
                    }
                }
            }
        }
    }
    __syncthreads();

    // ---------- phase 4: coalesced store (+ proj bias) ----------
    {
        const float4* st4 = (const float4*)outstage;
        const float4* pb4 = (const float4*)proj_b;
        float4* out4 = (float4*)(out + (size_t)wg * MROWS * DIM);
        #pragma unroll
        for (int i = 0; i < 15; ++i) {
            int idx = i * 256 + t;               // 0 .. 3839
            int c4 = idx % 96;
            float4 v = st4[idx];
            float4 b = pb4[c4];
            float4 r; r.x = v.x + b.x; r.y = v.y + b.y; r.z = v.z + b.z; r.w = v.w + b.w;
            out4[idx] = r;
        }
    }
}

extern "C" void kernel_launch(void* const* d_in, const int* in_sizes, int n_in,
                              void* d_out, int out_size, void* d_ws, size_t ws_size,
                              hipStream_t stream) {
    const float* x          = (const float*)d_in[0];
    const float* qkv_w      = (const float*)d_in[1];
    const float* qkv_b      = (const float*)d_in[2];
    const float* proj_w     = (const float*)d_in[3];
    const float* proj_b     = (const float*)d_in[4];
    const float* bias_table = (const float*)d_in[5];

    unsigned short* wq = (unsigned short*)d_ws;              // [1152][384] bf16
    unsigned short* wp = wq + (size_t)QKVDIM * DIM;          // [384][384] bf16
    float* out = (float*)d_out;

    convert_weights<<<576, 256, 0, stream>>>(qkv_w, proj_w, wq, wp);

    hipFuncSetAttribute((const void*)fused_attn,
                        hipFuncAttributeMaxDynamicSharedMemorySize, LDS_BYTES);
    fused_attn<<<16384 / NB, 256, LDS_BYTES, stream>>>(x, qkv_b, proj_b, bias_table, wq, wp, out);
}